// Round 10
// baseline (220.759 us; speedup 1.0000x reference)
//
#include <hip/hip_runtime.h>
#include <stdint.h>
#include <math.h>

#define B_   4
#define L_   2048
#define H_   16
#define DH_  64
#define DM_  1024

typedef __bf16 bf16;
typedef __attribute__((ext_vector_type(8))) __bf16 bf16x8;
typedef __attribute__((ext_vector_type(4))) float f32x4;
typedef __attribute__((ext_vector_type(4))) int i32x4;
typedef __attribute__((ext_vector_type(4))) short s16x4;
typedef unsigned short u16;
typedef unsigned int u32;
typedef __attribute__((ext_vector_type(2))) unsigned int u32x2;
typedef __attribute__((ext_vector_type(4))) unsigned short u16x4;

typedef unsigned int u32g __attribute__((address_space(1)));
typedef unsigned int u32l __attribute__((address_space(3)));

__device__ __forceinline__ u16 f2bf(float f) {
  return __builtin_bit_cast(u16, (bf16)f);   // fptrunc = RNE
}

// 2^x via the HW transcendental unit (scores are kept in log2 units)
__device__ __forceinline__ float exp2_fast(float x) {
  float r; asm("v_exp_f32 %0, %1" : "=v"(r) : "v"(x)); return r;
}

// async global->LDS 16B; LDS dest must be wave-uniform base + lane*16
__device__ __forceinline__ void gload16(const void* g, void* l) {
  __builtin_amdgcn_global_load_lds((const u32g*)g, (u32l*)l, 16, 0, 0);
}

// K=16 bf16 MFMA: A/B are 4 bf16 per lane with k=(lane>>4)*4+j — this matches
// the C-layout of the QK 16x16x32 MFMA, so P needs NO cross-lane transpose.
__device__ __forceinline__ f32x4 mfma16(s16x4 a, s16x4 b, f32x4 c) {
#if __has_builtin(__builtin_amdgcn_mfma_f32_16x16x16bf16_1k)
  return __builtin_amdgcn_mfma_f32_16x16x16bf16_1k(a, b, c, 0, 0, 0);
#else
  asm volatile("v_mfma_f32_16x16x16_bf16 %0, %1, %2, %0\n\ts_nop 7\n\ts_nop 2"
               : "+v"(c) : "v"(a), "v"(b));
  return c;
#endif
}

// ---------------- fused f32 -> bf16 conversion (x, Wqkv, Wout in one launch) ----------------
#define NX4 2097152                  // 8192*1024/4
#define NQ4 786432                   // 3072*1024/4
#define NO4 262144                   // 1024*1024/4
__global__ __launch_bounds__(256) void cvt3(const float* __restrict__ x,
                                            const float* __restrict__ wq,
                                            const float* __restrict__ wo,
                                            u16* __restrict__ xb, u16* __restrict__ wqb,
                                            u16* __restrict__ wob) {
  int i = blockIdx.x * 256 + threadIdx.x;    // grid covers exactly NX4+NQ4+NO4
  const float* src; u16* dst; int j;
  if (i < NX4)            { src = x;  dst = xb;  j = i; }
  else if (i < NX4 + NQ4) { src = wq; dst = wqb; j = i - NX4; }
  else                    { src = wo; dst = wob; j = i - NX4 - NQ4; }
  f32x4 v = ((const f32x4*)src)[j];
  u16x4 o;
  o[0] = f2bf(v[0]); o[1] = f2bf(v[1]); o[2] = f2bf(v[2]); o[3] = f2bf(v[3]);
  ((u16x4*)dst)[j] = o;
}

// ---------------- per-key bias table: Bk[bh][l] (log2 units) ----------------
__global__ __launch_bounds__(256) void bias_fill(const float* __restrict__ ts,
                                                 const float* __restrict__ msk,
                                                 const float* __restrict__ decay,
                                                 float* __restrict__ Bk) {
  int i = blockIdx.x * 256 + threadIdx.x;        // 64*2048
  int bh = i >> 11, l = i & (L_ - 1);
  int b = bh >> 4, h = bh & 15;
  float dc24 = log1pf(__expf(decay[h])) * (1.0f / 24.0f) * 1.44269504f;
  float tv = ts[b * L_ + l], mv = msk[b * L_ + l];
  Bk[i] = (mv != 0.f) ? dc24 * tv : -INFINITY;
}

// ---------------- bf16 GEMM (R17 verbatim) ----------------
__global__ __launch_bounds__(512) void gemm_bf16(
    const u16* __restrict__ A, const u16* __restrict__ Bm, const float* __restrict__ bias,
    int M, int N, int K, int mode,
    u16* __restrict__ Qb, u16* __restrict__ Kb, u16* __restrict__ Vt, float* __restrict__ Cout)
{
  __shared__ char smem[147456];     // 3 x (A 32KB + B 16KB); epilogue aliases
  u16* ltr = (u16*)smem;

  const int tid = threadIdx.x;
  // XCD-chunked bijective swizzle (gridDim.x % 8 == 0 for both launches)
  const int nwg = gridDim.x;
  int idx = blockIdx.x;
  idx = (idx & 7) * (nwg >> 3) + (idx >> 3);
  const int nbx = N >> 7;
  const int bx = idx % nbx, by = idx / nbx;
  const int m0 = by << 8, n0 = bx << 7;

  const int lane = tid & 63, w = tid >> 6;
  const int g = lane >> 4, col = lane & 15;
  const int wr = w >> 1, wc = w & 1;          // 4 M-waves x 2 N-waves

  f32x4 acc[4][4];
#pragma unroll
  for (int mt = 0; mt < 4; ++mt)
#pragma unroll
    for (int nt = 0; nt < 4; ++nt) {
      acc[mt][nt][0] = 0.f; acc[mt][nt][1] = 0.f;
      acc[mt][nt][2] = 0.f; acc[mt][nt][3] = 0.f;
    }

  // staging slices: A-half hh (2 loads/thread), B (2 loads/thread)
  auto STAGE_A = [&](int kt, int nb, int hh) {
    char* dA = smem + nb * 49152;
    const int k0 = kt << 6;
#pragma unroll
    for (int pp = hh * 2; pp < hh * 2 + 2; ++pp) {
      int c = tid + pp * 512;
      int row = c >> 3, cc = c & 7;
      gload16(A + (size_t)(m0 + row) * K + k0 + ((cc ^ (row & 7)) << 3), dA + c * 16);
    }
  };
  auto STAGE_B = [&](int kt, int nb) {
    char* dB = smem + nb * 49152 + 32768;
    const int k0 = kt << 6;
#pragma unroll
    for (int pp = 0; pp < 2; ++pp) {
      int c = tid + pp * 512;
      int row = c >> 3, cc = c & 7;
      gload16(Bm + (size_t)(n0 + row) * K + k0 + ((cc ^ (row & 7)) << 3), dB + c * 16);
    }
  };

  // prologue: tiles 0 and 1 staged full
  STAGE_A(0, 0, 0); STAGE_A(0, 0, 1); STAGE_B(0, 0);
  STAGE_A(1, 1, 0); STAGE_A(1, 1, 1); STAGE_B(1, 1);
  asm volatile("s_waitcnt vmcnt(6)" ::: "memory");   // tile 0 landed
  __builtin_amdgcn_s_barrier();

  const int nk = K >> 6;                       // 16
  for (int t = 0; t < nk; ++t) {
    const char* bufA = smem + (t % 3) * 49152;
    const char* bufB = bufA + 32768;
    const bool pf = (t + 2 < nk);
    const int nb2 = (t + 2) % 3;

    bf16x8 af[4][2], bfr[4][2];
    auto RDA = [&](int mt, int kk) {
      int row = wr * 64 + mt * 16 + col;
      return *(const bf16x8*)(bufA + row * 128 + ((((kk << 2) + g) ^ (row & 7)) << 4));
    };
    auto RDB = [&](int nt, int kk) {
      int row = wc * 64 + nt * 16 + col;
      return *(const bf16x8*)(bufB + row * 128 + ((((kk << 2) + g) ^ (row & 7)) << 4));
    };
    auto QUAD = [&](int qm, int qn) {
      __builtin_amdgcn_s_setprio(1);
#pragma unroll
      for (int mi = 0; mi < 2; ++mi)
#pragma unroll
        for (int ni = 0; ni < 2; ++ni)
#pragma unroll
          for (int kk = 0; kk < 2; ++kk)
            acc[qm * 2 + mi][qn * 2 + ni] = __builtin_amdgcn_mfma_f32_16x16x32_bf16(
                af[qm * 2 + mi][kk], bfr[qn * 2 + ni][kk], acc[qm * 2 + mi][qn * 2 + ni], 0, 0, 0);
      __builtin_amdgcn_s_setprio(0);
    };

    // ---- P1: (qm0,qn0) ----
#pragma unroll
    for (int mi = 0; mi < 2; ++mi) { af[mi][0] = RDA(mi, 0); af[mi][1] = RDA(mi, 1); }
#pragma unroll
    for (int ni = 0; ni < 2; ++ni) { bfr[ni][0] = RDB(ni, 0); bfr[ni][1] = RDB(ni, 1); }
    if (pf) STAGE_A(t + 2, nb2, 0);
    __builtin_amdgcn_s_barrier();
    asm volatile("s_waitcnt lgkmcnt(0)" ::: "memory");
    __builtin_amdgcn_sched_barrier(0);
    QUAD(0, 0);
    __builtin_amdgcn_s_barrier();

    // ---- P2: (qm0,qn1) ----
#pragma unroll
    for (int ni = 2; ni < 4; ++ni) { bfr[ni][0] = RDB(ni, 0); bfr[ni][1] = RDB(ni, 1); }
    if (pf) STAGE_A(t + 2, nb2, 1);
    __builtin_amdgcn_s_barrier();
    asm volatile("s_waitcnt lgkmcnt(0)" ::: "memory");
    __builtin_amdgcn_sched_barrier(0);
    QUAD(0, 1);
    __builtin_amdgcn_s_barrier();

    // ---- P3: (qm1,qn1) ----
#pragma unroll
    for (int mi = 2; mi < 4; ++mi) { af[mi][0] = RDA(mi, 0); af[mi][1] = RDA(mi, 1); }
    if (pf) STAGE_B(t + 2, nb2);
    __builtin_amdgcn_s_barrier();
    asm volatile("s_waitcnt lgkmcnt(0)" ::: "memory");
    __builtin_amdgcn_sched_barrier(0);
    QUAD(1, 1);
    __builtin_amdgcn_s_barrier();

    // ---- P4: (qm1,qn0) — pure MFMA, all operands live ----
    QUAD(1, 0);
    if (pf)              asm volatile("s_waitcnt vmcnt(6)" ::: "memory");  // t+1 landed
    else if (t + 1 < nk) asm volatile("s_waitcnt vmcnt(0)" ::: "memory");
    __builtin_amdgcn_s_barrier();
  }

  if (mode == 1) {
#pragma unroll
    for (int nt = 0; nt < 4; ++nt) {
      int gn = n0 + wc * 64 + nt * 16 + col;
      float bv = bias[gn];
#pragma unroll
      for (int mt = 0; mt < 4; ++mt) {
        int mbase = m0 + wr * 64 + mt * 16 + g * 4;
#pragma unroll
        for (int r = 0; r < 4; ++r)
          Cout[(size_t)(mbase + r) * N + gn] = acc[mt][nt][r] + bv;
      }
    }
    return;
  }

  // mode 0 epilogue via padded LDS transpose, aliasing staging.
  const int type = n0 >> 10;               // 0=q 1=k 2=v
  const float qsc = (type == 0) ? 0.125f * 1.44269504f : 1.0f;
#pragma unroll
  for (int nt = 0; nt < 4; ++nt) {
    int nn = wc * 64 + nt * 16 + col;
    float bv = bias[n0 + nn];
#pragma unroll
    for (int mt = 0; mt < 4; ++mt) {
      int mm = wr * 64 + mt * 16 + g * 4;
#pragma unroll
      for (int r = 0; r < 4; ++r) {
        u16 hv = f2bf((acc[mt][nt][r] + bv) * qsc);
        if (type < 2) ltr[(mm + r) * 136 + nn] = hv;
        else          ltr[nn * 264 + (mm + r)] = hv;
      }
    }
  }
  __syncthreads();
  if (type < 2) {
#pragma unroll
    for (int it = 0; it < 8; ++it) {
      int cid = tid + it * 512;
      int rrow = cid >> 4, cc = cid & 15;       // 256 rows x 16 chunks
      i32x4 v = *(const i32x4*)((const char*)ltr + rrow * 272 + cc * 16);
      int token = m0 + rrow;
      int bb = token >> 11, ll = token & (L_ - 1);
      int gn = n0 + cc * 8;
      int head = (gn & 1023) >> 6, d = gn & 63;
      u16* dst = (type == 0) ? Qb : Kb;
      *(i32x4*)(dst + ((size_t)((bb * H_ + head) * L_ + ll)) * 64 + d) = v;
    }
  } else {
#pragma unroll
    for (int it = 0; it < 8; ++it) {
      int cid = tid + it * 512;
      int rrow = cid >> 5, cc = cid & 31;       // 128 rows x 32 chunks
      i32x4 v = *(const i32x4*)((const char*)ltr + rrow * 528 + cc * 16);
      int gn = n0 + rrow;
      int head = (gn & 1023) >> 6, d = gn & 63;
      int token0 = m0 + cc * 8;
      int bb = token0 >> 11, ll = token0 & (L_ - 1);
      *(i32x4*)(Vt + ((size_t)((bb * H_ + head) * DH_ + d)) * L_ + ll) = v;
    }
  }
}

// ---------------- fused temporal flash attention ----------------
// R19 = R18 + A/B WORK-SHARING over the common causal prefix:
//  * One k-loop 0..nkB-1 (nkB=2(qbt+1)). Since qbt>qa always, tile A's range
//    (kt<nkA) is a prefix of B's: those tiles are staged ONCE and both bodies
//    run on them, SHARING the K-fragment reads (same MFMA A-operand) and the
//    V-fragment reads (same PV A-operand). LDS reads / barriers / staging
//    drop by nkA/(nkA+nkB) ~ 26% avg vs R18's sequential double pipeline.
//  * Bodies/block stay exactly 34 (uniform); steps vary 18..32 but worst-case
//    CU pairing (2x pr=0 = 64 step-units) < R18's uniform 68.
//  * Dual state (oA/oB, qfA/qfB, lA/lB, mnA/mnB) ~ +45 VGPR over measured 44
//    -> ~95, under the 128 cap at 2 blocks/CU (R11 spilled only at cap 64).
__global__ __launch_bounds__(512, 2) void attn_fwd(
    const u16* __restrict__ Qb, const u16* __restrict__ Kb, const u16* __restrict__ Vt,
    const float* __restrict__ Bk, u16* __restrict__ AO)
{
  __shared__ u16 lK[3][64 * 64];     // [key][dh] swz ^(key&7)   24KB
  __shared__ u16 lV[3][64 * 64];     // [d][key]  swz ^(d&7)     24KB => 48KB

  const int phys = blockIdx.x;            // 512 blocks
  const int xcd = phys & 7, s = phys >> 3;
  const int bh = xcd * 8 + (s >> 3);
  const int pr = s & 7;
  const int qa = pr, qbt = 15 - pr;       // qa < qbt always
  const int b = bh >> 4, h = bh & 15;

  const int tid = threadIdx.x, w = tid >> 6, lane = tid & 63;
  const int g = lane >> 4, q16 = lane & 15;

  const float* Bkb = Bk + (size_t)bh * L_;

  // per-lane LDS column offsets (swizzle-resolved once)
  int kcol[2], vcol[4];
#pragma unroll
  for (int kk = 0; kk < 2; ++kk) kcol[kk] = ((kk * 4 + g) ^ (q16 & 7)) << 4;
#pragma unroll
  for (int t = 0; t < 4; ++t)
    vcol[t] = (((2 * t + (g >> 1)) ^ (q16 & 7)) << 4) + (g & 1) * 8;

  const int nkA = (qa + 1) * 2;           // shared prefix length (2..16)
  const int nkB = (qbt + 1) * 2;          // total steps (18..32)

  const int qrowA = qa * 128 + w * 16, qrowB = qbt * 128 + w * 16;
  const int mktA = (qrowA + 79) >> 6;     // <= nkA
  const int mktB = (qrowB + 79) >> 6;     // <= nkB
  const float mnA = Bkb[qrowA + q16] + 8.f;   // static row normalizers (R18)
  const float mnB = Bkb[qrowB + q16] + 8.f;

  bf16x8 qfA[2], qfB[2];
  {
    const u16* Qr = Qb + ((size_t)bh * L_ + qrowA + q16) * 64;
    qfA[0] = *(const bf16x8*)(Qr + g * 8);
    qfA[1] = *(const bf16x8*)(Qr + 32 + g * 8);
    Qr = Qb + ((size_t)bh * L_ + qrowB + q16) * 64;
    qfB[0] = *(const bf16x8*)(Qr + g * 8);
    qfB[1] = *(const bf16x8*)(Qr + 32 + g * 8);
  }

  float lA = 0.f, lB = 0.f;
  f32x4 oA[4], oB[4];
#pragma unroll
  for (int db = 0; db < 4; ++db) {
    oA[db][0] = 0.f; oA[db][1] = 0.f; oA[db][2] = 0.f; oA[db][3] = 0.f;
    oB[db][0] = 0.f; oB[db][1] = 0.f; oB[db][2] = 0.f; oB[db][3] = 0.f;
  }

  auto STAGE = [&](int kt, int nb) {
    const int kg0 = kt * 64;
    const int r8 = tid >> 3, cc = tid & 7;   // 512 threads: 64 rows x 8 granules
    gload16(Kb + ((size_t)bh * L_ + kg0 + r8) * 64 + ((cc ^ (r8 & 7)) * 8),
            (char*)lK[nb] + tid * 16);
    gload16(Vt + ((size_t)(bh * 64 + r8)) * L_ + kg0 + ((cc ^ (r8 & 7)) * 8),
            (char*)lV[nb] + tid * 16);
  };

  // doA is a compile-time-specialized flag (called with literals only).
  auto BODY = [&](bool doA, int kg0, int cur) {
    // per-key bias as C-init for BOTH tiles (bias depends on key only)
    f32x4 bk[4];
#pragma unroll
    for (int t = 0; t < 4; ++t)
      bk[t] = *(const f32x4*)(Bkb + kg0 + t * 16 + g * 4);

    f32x4 svA[4], svB[4];
#pragma unroll
    for (int t = 0; t < 4; ++t) { if (doA) svA[t] = bk[t]; svB[t] = bk[t]; }

    // ---- shared-K QK: one kf read feeds both tiles' MFMAs ----
    __builtin_amdgcn_s_setprio(1);
#pragma unroll
    for (int t = 0; t < 4; ++t) {
      const char* krow = (const char*)lK[cur] + t * 2048 + q16 * 128;
#pragma unroll
      for (int kk = 0; kk < 2; ++kk) {
        bf16x8 kf = *(const bf16x8*)(krow + kcol[kk]);
        if (doA) svA[t] = __builtin_amdgcn_mfma_f32_16x16x32_bf16(kf, qfA[kk], svA[t], 0, 0, 0);
        svB[t] = __builtin_amdgcn_mfma_f32_16x16x32_bf16(kf, qfB[kk], svB[t], 0, 0, 0);
      }
    }
    __builtin_amdgcn_s_setprio(0);

    // ---- causal masks (diagonal tiles only; wave-uniform) ----
    if (doA && kg0 + 63 > qrowA) {
      const int qg = qrowA + q16;
#pragma unroll
      for (int t = 0; t < 4; ++t)
#pragma unroll
        for (int r = 0; r < 4; ++r)
          svA[t][r] = (kg0 + t * 16 + g * 4 + r <= qg) ? svA[t][r] : -INFINITY;
    }
    if (kg0 + 63 > qrowB) {
      const int qg = qrowB + q16;
#pragma unroll
      for (int t = 0; t < 4; ++t)
#pragma unroll
        for (int r = 0; r < 4; ++r)
          svB[t][r] = (kg0 + t * 16 + g * 4 + r <= qg) ? svB[t][r] : -INFINITY;
    }

    // ---- static-normalizer softmax + pack, per tile ----
    s16x4 pfA[4], pfB[4];
    if (doA) {
      float rs = 0.f;
#pragma unroll
      for (int t = 0; t < 4; ++t) {
        s16x4 pp;
#pragma unroll
        for (int r = 0; r < 4; ++r) {
          float pv = exp2_fast(svA[t][r] - mnA);
          rs += pv;
          pp[r] = (short)f2bf(pv);
        }
        pfA[t] = pp;
      }
      lA += rs;
    }
    {
      float rs = 0.f;
#pragma unroll
      for (int t = 0; t < 4; ++t) {
        s16x4 pp;
#pragma unroll
        for (int r = 0; r < 4; ++r) {
          float pv = exp2_fast(svB[t][r] - mnB);
          rs += pv;
          pp[r] = (short)f2bf(pv);
        }
        pfB[t] = pp;
      }
      lB += rs;
    }

    // ---- shared-V PV: one vf read feeds both tiles' MFMAs ----
    __builtin_amdgcn_s_setprio(1);
#pragma unroll
    for (int t = 0; t < 4; ++t) {
      const char* vrow = (const char*)lV[cur] + q16 * 128 + vcol[t];
#pragma unroll
      for (int db = 0; db < 4; ++db) {
        s16x4 vf = *(const s16x4*)(vrow + db * 2048);
        if (doA) oA[db] = mfma16(vf, pfA[t], oA[db]);
        oB[db] = mfma16(vf, pfB[t], oB[db]);
      }
    }
    __builtin_amdgcn_s_setprio(0);
  };

  // direct global epilogue (unchanged)
  auto EPI = [&](f32x4 (&o)[4], float l_r, int qt) {
    float lt = l_r + __shfl_xor(l_r, 16);
    lt += __shfl_xor(lt, 32);
    float inv = 1.f / lt;
    u16* dst = AO + ((size_t)(b * L_ + qt * 128 + w * 16 + q16)) * DM_ + h * 64 + g * 4;
#pragma unroll
    for (int db = 0; db < 4; ++db) {
      u32x2 pk;
      pk[0] = (u32)f2bf(o[db][0] * inv) | ((u32)f2bf(o[db][1] * inv) << 16);
      pk[1] = (u32)f2bf(o[db][2] * inv) | ((u32)f2bf(o[db][3] * inv) << 16);
      *(u32x2*)(dst + db * 16) = pk;
    }
  };

  // ---- prologue: fill pipeline 2 deep ----
  STAGE(0, 0);
  STAGE(1, 1);
  asm volatile("s_waitcnt vmcnt(2) lgkmcnt(0)" ::: "memory");   // S[0] landed
  __builtin_amdgcn_s_barrier();
  __builtin_amdgcn_sched_barrier(0);

  // ---- single fused k-loop ----
  for (int kt = 0; kt < nkB; ++kt) {
    const int cur = kt % 3;
    const bool pf = (kt + 2 < nkB);
    if (pf) STAGE(kt + 2, (kt + 2) % 3);
    if (kt < mktA)      BODY(true,  kt * 64, cur);   // shared prefix: both tiles
    else if (kt < mktB) BODY(false, kt * 64, cur);   // B only
    if (kt + 1 < nkB) {
      if (pf) asm volatile("s_waitcnt vmcnt(2) lgkmcnt(0)" ::: "memory");
      else    asm volatile("s_waitcnt vmcnt(0) lgkmcnt(0)" ::: "memory");
      __builtin_amdgcn_s_barrier();
      __builtin_amdgcn_sched_barrier(0);
    }
  }
  EPI(oA, lA, qa);
  EPI(oB, lB, qbt);
}

// ---------------- launcher ----------------
extern "C" void kernel_launch(void* const* d_in, const int* in_sizes, int n_in,
                              void* d_out, int out_size, void* d_ws, size_t ws_size,
                              hipStream_t stream) {
  const float* x    = (const float*)d_in[0];
  const float* ts   = (const float*)d_in[1];
  const float* mk   = (const float*)d_in[2];
  const float* Wqkv = (const float*)d_in[3];
  const float* bqkv = (const float*)d_in[4];
  const float* Wout = (const float*)d_in[5];
  const float* bout = (const float*)d_in[6];
  const float* dec  = (const float*)d_in[7];
  float* out = (float*)d_out;

  char* ws = (char*)d_ws;
  u16* xbf  = (u16*)(ws + 0);
  u16* wqbf = (u16*)(ws + 16777216);
  u16* wobf = (u16*)(ws + 23068672);
  u16* Qb   = (u16*)(ws + 25165824);
  u16* Kb   = (u16*)(ws + 41943040);
  u16* Vt   = (u16*)(ws + 58720256);
  u16* AO   = (u16*)(ws + 75497472);
  float* Bk = (float*)(ws + 92274688);   // 64*2048*4 = 512KB

  cvt3<<<dim3((NX4 + NQ4 + NO4) / 256), 256, 0, stream>>>(x, Wqkv, Wout, xbf, wqbf, wobf);

  bias_fill<<<dim3(64 * 2048 / 256), 256, 0, stream>>>(ts, mk, dec, Bk);

  // 256x128 tile: grid = (8192/256) * (3072/128) = 768 blocks
  gemm_bf16<<<dim3(768), 512, 0, stream>>>(
      xbf, wqbf, bqkv, 8192, 3072, 1024, 0, Qb, Kb, Vt, nullptr);

  attn_fwd<<<dim3(512), 512, 0, stream>>>(Qb, Kb, Vt, Bk, AO);

  // grid = (8192/256) * (1024/128) = 256 blocks
  gemm_bf16<<<dim3(256), 512, 0, stream>>>(
      AO, wobf, bout, 8192, 1024, 1024, 1, nullptr, nullptr, nullptr, out);
}

// Round 11
// 174.380 us; speedup vs baseline: 1.2660x; 1.2660x over previous
//
#include <hip/hip_runtime.h>
#include <stdint.h>
#include <math.h>

#define B_   4
#define L_   2048
#define H_   16
#define DH_  64
#define DM_  1024

typedef __bf16 bf16;
typedef __attribute__((ext_vector_type(8))) __bf16 bf16x8;
typedef __attribute__((ext_vector_type(4))) float f32x4;
typedef __attribute__((ext_vector_type(4))) int i32x4;
typedef __attribute__((ext_vector_type(4))) short s16x4;
typedef unsigned short u16;
typedef unsigned int u32;
typedef __attribute__((ext_vector_type(2))) unsigned int u32x2;
typedef __attribute__((ext_vector_type(4))) unsigned short u16x4;

typedef unsigned int u32g __attribute__((address_space(1)));
typedef unsigned int u32l __attribute__((address_space(3)));

__device__ __forceinline__ u16 f2bf(float f) {
  return __builtin_bit_cast(u16, (bf16)f);   // fptrunc = RNE
}

// 2^x via the HW transcendental unit (scores are kept in log2 units)
__device__ __forceinline__ float exp2_fast(float x) {
  float r; asm("v_exp_f32 %0, %1" : "=v"(r) : "v"(x)); return r;
}

// async global->LDS 16B; LDS dest must be wave-uniform base + lane*16
__device__ __forceinline__ void gload16(const void* g, void* l) {
  __builtin_amdgcn_global_load_lds((const u32g*)g, (u32l*)l, 16, 0, 0);
}

// K=16 bf16 MFMA: A/B are 4 bf16 per lane with k=(lane>>4)*4+j — this matches
// the C-layout of the QK 16x16x32 MFMA, so P needs NO cross-lane transpose.
__device__ __forceinline__ f32x4 mfma16(s16x4 a, s16x4 b, f32x4 c) {
#if __has_builtin(__builtin_amdgcn_mfma_f32_16x16x16bf16_1k)
  return __builtin_amdgcn_mfma_f32_16x16x16bf16_1k(a, b, c, 0, 0, 0);
#else
  asm volatile("v_mfma_f32_16x16x16_bf16 %0, %1, %2, %0\n\ts_nop 7\n\ts_nop 2"
               : "+v"(c) : "v"(a), "v"(b));
  return c;
#endif
}

// ---------------- fused f32 -> bf16 conversion (x, Wqkv, Wout in one launch) ----------------
#define NX4 2097152                  // 8192*1024/4
#define NQ4 786432                   // 3072*1024/4
#define NO4 262144                   // 1024*1024/4
__global__ __launch_bounds__(256) void cvt3(const float* __restrict__ x,
                                            const float* __restrict__ wq,
                                            const float* __restrict__ wo,
                                            u16* __restrict__ xb, u16* __restrict__ wqb,
                                            u16* __restrict__ wob) {
  int i = blockIdx.x * 256 + threadIdx.x;    // grid covers exactly NX4+NQ4+NO4
  const float* src; u16* dst; int j;
  if (i < NX4)            { src = x;  dst = xb;  j = i; }
  else if (i < NX4 + NQ4) { src = wq; dst = wqb; j = i - NX4; }
  else                    { src = wo; dst = wob; j = i - NX4 - NQ4; }
  f32x4 v = ((const f32x4*)src)[j];
  u16x4 o;
  o[0] = f2bf(v[0]); o[1] = f2bf(v[1]); o[2] = f2bf(v[2]); o[3] = f2bf(v[3]);
  ((u16x4*)dst)[j] = o;
}

// ---------------- per-key bias table: Bk[bh][l] (log2 units) ----------------
__global__ __launch_bounds__(256) void bias_fill(const float* __restrict__ ts,
                                                 const float* __restrict__ msk,
                                                 const float* __restrict__ decay,
                                                 float* __restrict__ Bk) {
  int i = blockIdx.x * 256 + threadIdx.x;        // 64*2048
  int bh = i >> 11, l = i & (L_ - 1);
  int b = bh >> 4, h = bh & 15;
  float dc24 = log1pf(__expf(decay[h])) * (1.0f / 24.0f) * 1.44269504f;
  float tv = ts[b * L_ + l], mv = msk[b * L_ + l];
  Bk[i] = (mv != 0.f) ? dc24 * tv : -INFINITY;
}

// ---------------- QKV GEMM: 256x256 tile, true m198-geometry 8-wave 128x64/wave ----------------
// R20: BM=BN=256, BK=64, 512 thr = 2M x 4N waves, acc[8][4] (128 VGPR).
// 2 x 64KB LDS buffers; tile t in buf(t&1). Quarter-granular staggered staging
// (2 gload16/thread/phase) so ONE counted vmcnt(6) per K-tile suffices:
//   tile t+2's loads issue at t.P2 (A q0,q2), t.P3 (B c0,c1), t.P4 (A q1,q3),
//   (t+1).P1 (B c2,c3). At t.P4 the 6 newest outstanding are t+2's P2/P3/P4
//   loads -> vmcnt(6) forces tile t+1 (7th+ oldest) complete. Regions proven
//   free before each overwrite by the phase end-barriers:
//   A q0/q2 read only in P1, q1/q3 only in P3; B fully read by end of P2.
// Phases (quadrants of the wave's 128x64 C):
//   P1 (m-lo, n-lo): read af[0..3],bfr[0..1] | stage | bar | lgkm0 | 16 MFMA | bar
//   P2 (m-lo, n-hi): read bfr[2..3]          | stage | bar | lgkm0 | 16 MFMA | bar
//   P3 (m-hi, n-hi): read af[4..7]           | stage | bar | lgkm0 | 16 MFMA | bar
//   P4 (m-hi, n-lo): pure MFMA | stage | vmcnt(6) | bar
__global__ __launch_bounds__(512) void gemm_qkv(
    const u16* __restrict__ A, const u16* __restrict__ Bm, const float* __restrict__ bias,
    u16* __restrict__ Qb, u16* __restrict__ Kb, u16* __restrict__ Vt)
{
  __shared__ char smem[135168];     // 2 x (A 32KB + B 32KB) = 128KB; epi ltr[256][264]
  u16* ltr = (u16*)smem;
  const int K = 1024, nk = 16;

  const int tid = threadIdx.x;
  const int nwg = gridDim.x;              // 384, %8==0
  int idx = blockIdx.x;
  idx = (idx & 7) * (nwg >> 3) + (idx >> 3);
  const int nbx = 12;                     // N=3072 / 256
  const int bx = idx % nbx, by = idx / nbx;
  const int m0 = by << 8, n0 = bx << 8;

  const int lane = tid & 63, w = tid >> 6;
  const int g = lane >> 4, col = lane & 15;
  const int wr = w >> 2, wc = w & 3;      // 2M x 4N; per-wave C = 128 x 64

  f32x4 acc[8][4];
#pragma unroll
  for (int mt = 0; mt < 8; ++mt)
#pragma unroll
    for (int nt = 0; nt < 4; ++nt) {
      acc[mt][nt][0] = 0.f; acc[mt][nt][1] = 0.f;
      acc[mt][nt][2] = 0.f; acc[mt][nt][3] = 0.f;
    }

  // stage A quarter q (rows q*64..q*64+63) of tile kt into buf nb — 1 load/thread
  auto SA = [&](int kt, int nb, int q) {
    char* dA = smem + (nb << 16);
    int c = (q << 9) + tid;
    int row = c >> 3, cc = c & 7;
    gload16(A + (size_t)(m0 + row) * K + (kt << 6) + ((cc ^ (row & 7)) << 3), dA + c * 16);
  };
  // stage B chunk q (rows q*64..q*64+63)
  auto SB = [&](int kt, int nb, int q) {
    char* dB = smem + (nb << 16) + 32768;
    int c = (q << 9) + tid;
    int row = c >> 3, cc = c & 7;
    gload16(Bm + (size_t)(n0 + row) * K + (kt << 6) + ((cc ^ (row & 7)) << 3), dB + c * 16);
  };

  // prologue: tile 0 full (8), tile 1 partial (6; B c2,c3 deferred to t=0 P1)
  SA(0, 0, 0); SA(0, 0, 1); SA(0, 0, 2); SA(0, 0, 3);
  SB(0, 0, 0); SB(0, 0, 1); SB(0, 0, 2); SB(0, 0, 3);
  SA(1, 1, 0); SA(1, 1, 2); SB(1, 1, 0); SB(1, 1, 1); SA(1, 1, 1); SA(1, 1, 3);
  asm volatile("s_waitcnt vmcnt(6)" ::: "memory");   // tile 0 landed
  __builtin_amdgcn_s_barrier();

  for (int t = 0; t < nk; ++t) {
    const char* bufA = smem + ((t & 1) << 16);
    const char* bufB = bufA + 32768;
    const int nbN = (t + 1) & 1;          // buffer of tile t+1 (and t's own = t&1)

    auto RDA = [&](int mt, int kk) {
      int row = wr * 128 + mt * 16 + col;
      return *(const bf16x8*)(bufA + row * 128 + ((((kk << 2) + g) ^ (row & 7)) << 4));
    };
    auto RDB = [&](int nt, int kk) {
      int row = wc * 64 + nt * 16 + col;
      return *(const bf16x8*)(bufB + row * 128 + ((((kk << 2) + g) ^ (row & 7)) << 4));
    };

    bf16x8 af[4][2], bfr[4][2];

    // ---- P1: (m-lo, n-lo) ----
#pragma unroll
    for (int mi = 0; mi < 4; ++mi) { af[mi][0] = RDA(mi, 0); af[mi][1] = RDA(mi, 1); }
#pragma unroll
    for (int ni = 0; ni < 2; ++ni) { bfr[ni][0] = RDB(ni, 0); bfr[ni][1] = RDB(ni, 1); }
    if (t + 1 < nk) { SB(t + 1, nbN, 2); SB(t + 1, nbN, 3); }
    __builtin_amdgcn_s_barrier();
    asm volatile("s_waitcnt lgkmcnt(0)" ::: "memory");
    __builtin_amdgcn_sched_barrier(0);
    __builtin_amdgcn_s_setprio(1);
#pragma unroll
    for (int mi = 0; mi < 4; ++mi)
#pragma unroll
      for (int ni = 0; ni < 2; ++ni)
#pragma unroll
        for (int kk = 0; kk < 2; ++kk)
          acc[mi][ni] = __builtin_amdgcn_mfma_f32_16x16x32_bf16(af[mi][kk], bfr[ni][kk], acc[mi][ni], 0, 0, 0);
    __builtin_amdgcn_s_setprio(0);
    __builtin_amdgcn_s_barrier();

    // ---- P2: (m-lo, n-hi) ----
#pragma unroll
    for (int ni = 2; ni < 4; ++ni) { bfr[ni][0] = RDB(ni, 0); bfr[ni][1] = RDB(ni, 1); }
    if (t + 2 < nk) { SA(t + 2, t & 1, 0); SA(t + 2, t & 1, 2); }
    __builtin_amdgcn_s_barrier();
    asm volatile("s_waitcnt lgkmcnt(0)" ::: "memory");
    __builtin_amdgcn_sched_barrier(0);
    __builtin_amdgcn_s_setprio(1);
#pragma unroll
    for (int mi = 0; mi < 4; ++mi)
#pragma unroll
      for (int ni = 2; ni < 4; ++ni)
#pragma unroll
        for (int kk = 0; kk < 2; ++kk)
          acc[mi][ni] = __builtin_amdgcn_mfma_f32_16x16x32_bf16(af[mi][kk], bfr[ni][kk], acc[mi][ni], 0, 0, 0);
    __builtin_amdgcn_s_setprio(0);
    __builtin_amdgcn_s_barrier();

    // ---- P3: (m-hi, n-hi) — af[] reused for rows mt+4 ----
#pragma unroll
    for (int mi = 0; mi < 4; ++mi) { af[mi][0] = RDA(mi + 4, 0); af[mi][1] = RDA(mi + 4, 1); }
    if (t + 2 < nk) { SB(t + 2, t & 1, 0); SB(t + 2, t & 1, 1); }
    __builtin_amdgcn_s_barrier();
    asm volatile("s_waitcnt lgkmcnt(0)" ::: "memory");
    __builtin_amdgcn_sched_barrier(0);
    __builtin_amdgcn_s_setprio(1);
#pragma unroll
    for (int mi = 0; mi < 4; ++mi)
#pragma unroll
      for (int ni = 2; ni < 4; ++ni)
#pragma unroll
        for (int kk = 0; kk < 2; ++kk)
          acc[mi + 4][ni] = __builtin_amdgcn_mfma_f32_16x16x32_bf16(af[mi][kk], bfr[ni][kk], acc[mi + 4][ni], 0, 0, 0);
    __builtin_amdgcn_s_setprio(0);
    __builtin_amdgcn_s_barrier();

    // ---- P4: (m-hi, n-lo) — pure MFMA; stage; counted wait ----
    if (t + 2 < nk) { SA(t + 2, t & 1, 1); SA(t + 2, t & 1, 3); }
    __builtin_amdgcn_s_setprio(1);
#pragma unroll
    for (int mi = 0; mi < 4; ++mi)
#pragma unroll
      for (int ni = 0; ni < 2; ++ni)
#pragma unroll
        for (int kk = 0; kk < 2; ++kk)
          acc[mi + 4][ni] = __builtin_amdgcn_mfma_f32_16x16x32_bf16(af[mi][kk], bfr[ni][kk], acc[mi + 4][ni], 0, 0, 0);
    __builtin_amdgcn_s_setprio(0);
    if (t + 2 < nk) asm volatile("s_waitcnt vmcnt(6)" ::: "memory");  // t+1 fully landed
    else            asm volatile("s_waitcnt vmcnt(0)" ::: "memory");  // tail drain
    __builtin_amdgcn_s_barrier();
  }

  // ---- mode-0 epilogue via padded LDS transpose: ltr[256][264] u16 ----
  const int type = n0 >> 10;               // 0=q 1=k 2=v (256 | 1024 so uniform per block)
  const float qsc = (type == 0) ? 0.125f * 1.44269504f : 1.0f;
#pragma unroll
  for (int nt = 0; nt < 4; ++nt) {
    int nn = wc * 64 + nt * 16 + col;
    float bv = bias[n0 + nn];
#pragma unroll
    for (int mt = 0; mt < 8; ++mt) {
      int mm = wr * 128 + mt * 16 + g * 4;
#pragma unroll
      for (int r = 0; r < 4; ++r) {
        u16 hv = f2bf((acc[mt][nt][r] + bv) * qsc);
        if (type < 2) ltr[(mm + r) * 264 + nn] = hv;
        else          ltr[nn * 264 + (mm + r)] = hv;
      }
    }
  }
  __syncthreads();
  if (type < 2) {
#pragma unroll
    for (int it = 0; it < 16; ++it) {
      int cid = tid + it * 512;
      int rrow = cid >> 5, cc = cid & 31;       // 256 m-rows x 32 n-chunks
      i32x4 v = *(const i32x4*)((const char*)ltr + rrow * 528 + cc * 16);
      int token = m0 + rrow;
      int bb = token >> 11, ll = token & (L_ - 1);
      int gn = n0 + cc * 8;
      int head = (gn & 1023) >> 6, d = gn & 63;
      u16* dst = (type == 0) ? Qb : Kb;
      *(i32x4*)(dst + ((size_t)((bb * H_ + head) * L_ + ll)) * 64 + d) = v;
    }
  } else {
#pragma unroll
    for (int it = 0; it < 16; ++it) {
      int cid = tid + it * 512;
      int rrow = cid >> 5, cc = cid & 31;       // 256 n-rows x 32 m-chunks
      i32x4 v = *(const i32x4*)((const char*)ltr + rrow * 528 + cc * 16);
      int gn = n0 + rrow;
      int head = (gn & 1023) >> 6, d = gn & 63;
      int token0 = m0 + cc * 8;
      int bb = token0 >> 11, ll = token0 & (L_ - 1);
      *(i32x4*)(Vt + ((size_t)((bb * H_ + head) * DH_ + d)) * L_ + ll) = v;
    }
  }
}

// ---------------- bf16 GEMM (R17 verbatim — used for the mode-1 output GEMM) ----------------
__global__ __launch_bounds__(512) void gemm_bf16(
    const u16* __restrict__ A, const u16* __restrict__ Bm, const float* __restrict__ bias,
    int M, int N, int K, int mode,
    u16* __restrict__ Qb, u16* __restrict__ Kb, u16* __restrict__ Vt, float* __restrict__ Cout)
{
  __shared__ char smem[147456];     // 3 x (A 32KB + B 16KB)
  const int tid = threadIdx.x;
  const int nwg = gridDim.x;
  int idx = blockIdx.x;
  idx = (idx & 7) * (nwg >> 3) + (idx >> 3);
  const int nbx = N >> 7;
  const int bx = idx % nbx, by = idx / nbx;
  const int m0 = by << 8, n0 = bx << 7;

  const int lane = tid & 63, w = tid >> 6;
  const int g = lane >> 4, col = lane & 15;
  const int wr = w >> 1, wc = w & 1;          // 4 M-waves x 2 N-waves

  f32x4 acc[4][4];
#pragma unroll
  for (int mt = 0; mt < 4; ++mt)
#pragma unroll
    for (int nt = 0; nt < 4; ++nt) {
      acc[mt][nt][0] = 0.f; acc[mt][nt][1] = 0.f;
      acc[mt][nt][2] = 0.f; acc[mt][nt][3] = 0.f;
    }

  auto STAGE_A = [&](int kt, int nb, int hh) {
    char* dA = smem + nb * 49152;
    const int k0 = kt << 6;
#pragma unroll
    for (int pp = hh * 2; pp < hh * 2 + 2; ++pp) {
      int c = tid + pp * 512;
      int row = c >> 3, cc = c & 7;
      gload16(A + (size_t)(m0 + row) * K + k0 + ((cc ^ (row & 7)) << 3), dA + c * 16);
    }
  };
  auto STAGE_B = [&](int kt, int nb) {
    char* dB = smem + nb * 49152 + 32768;
    const int k0 = kt << 6;
#pragma unroll
    for (int pp = 0; pp < 2; ++pp) {
      int c = tid + pp * 512;
      int row = c >> 3, cc = c & 7;
      gload16(Bm + (size_t)(n0 + row) * K + k0 + ((cc ^ (row & 7)) << 3), dB + c * 16);
    }
  };

  STAGE_A(0, 0, 0); STAGE_A(0, 0, 1); STAGE_B(0, 0);
  STAGE_A(1, 1, 0); STAGE_A(1, 1, 1); STAGE_B(1, 1);
  asm volatile("s_waitcnt vmcnt(6)" ::: "memory");
  __builtin_amdgcn_s_barrier();

  const int nk = K >> 6;                       // 16
  for (int t = 0; t < nk; ++t) {
    const char* bufA = smem + (t % 3) * 49152;
    const char* bufB = bufA + 32768;
    const bool pf = (t + 2 < nk);
    const int nb2 = (t + 2) % 3;

    bf16x8 af[4][2], bfr[4][2];
    auto RDA = [&](int mt, int kk) {
      int row = wr * 64 + mt * 16 + col;
      return *(const bf16x8*)(bufA + row * 128 + ((((kk << 2) + g) ^ (row & 7)) << 4));
    };
    auto RDB = [&](int nt, int kk) {
      int row = wc * 64 + nt * 16 + col;
      return *(const bf16x8*)(bufB + row * 128 + ((((kk << 2) + g) ^ (row & 7)) << 4));
    };
    auto QUAD = [&](int qm, int qn) {
      __builtin_amdgcn_s_setprio(1);
#pragma unroll
      for (int mi = 0; mi < 2; ++mi)
#pragma unroll
        for (int ni = 0; ni < 2; ++ni)
#pragma unroll
          for (int kk = 0; kk < 2; ++kk)
            acc[qm * 2 + mi][qn * 2 + ni] = __builtin_amdgcn_mfma_f32_16x16x32_bf16(
                af[qm * 2 + mi][kk], bfr[qn * 2 + ni][kk], acc[qm * 2 + mi][qn * 2 + ni], 0, 0, 0);
      __builtin_amdgcn_s_setprio(0);
    };

#pragma unroll
    for (int mi = 0; mi < 2; ++mi) { af[mi][0] = RDA(mi, 0); af[mi][1] = RDA(mi, 1); }
#pragma unroll
    for (int ni = 0; ni < 2; ++ni) { bfr[ni][0] = RDB(ni, 0); bfr[ni][1] = RDB(ni, 1); }
    if (pf) STAGE_A(t + 2, nb2, 0);
    __builtin_amdgcn_s_barrier();
    asm volatile("s_waitcnt lgkmcnt(0)" ::: "memory");
    __builtin_amdgcn_sched_barrier(0);
    QUAD(0, 0);
    __builtin_amdgcn_s_barrier();

#pragma unroll
    for (int ni = 2; ni < 4; ++ni) { bfr[ni][0] = RDB(ni, 0); bfr[ni][1] = RDB(ni, 1); }
    if (pf) STAGE_A(t + 2, nb2, 1);
    __builtin_amdgcn_s_barrier();
    asm volatile("s_waitcnt lgkmcnt(0)" ::: "memory");
    __builtin_amdgcn_sched_barrier(0);
    QUAD(0, 1);
    __builtin_amdgcn_s_barrier();

#pragma unroll
    for (int mi = 2; mi < 4; ++mi) { af[mi][0] = RDA(mi, 0); af[mi][1] = RDA(mi, 1); }
    if (pf) STAGE_B(t + 2, nb2);
    __builtin_amdgcn_s_barrier();
    asm volatile("s_waitcnt lgkmcnt(0)" ::: "memory");
    __builtin_amdgcn_sched_barrier(0);
    QUAD(1, 1);
    __builtin_amdgcn_s_barrier();

    QUAD(1, 0);
    if (pf)              asm volatile("s_waitcnt vmcnt(6)" ::: "memory");
    else if (t + 1 < nk) asm volatile("s_waitcnt vmcnt(0)" ::: "memory");
    __builtin_amdgcn_s_barrier();
  }

  // mode 1 epilogue only (mode 0 now handled by gemm_qkv)
#pragma unroll
  for (int nt = 0; nt < 4; ++nt) {
    int gn = n0 + wc * 64 + nt * 16 + col;
    float bv = bias[gn];
#pragma unroll
    for (int mt = 0; mt < 4; ++mt) {
      int mbase = m0 + wr * 64 + mt * 16 + g * 4;
#pragma unroll
      for (int r = 0; r < 4; ++r)
        Cout[(size_t)(mbase + r) * N + gn] = acc[mt][nt][r] + bv;
    }
  }
}

// ---------------- fused temporal flash attention (R18 verbatim — best measured) ----------------
__global__ __launch_bounds__(512, 2) void attn_fwd(
    const u16* __restrict__ Qb, const u16* __restrict__ Kb, const u16* __restrict__ Vt,
    const float* __restrict__ Bk, u16* __restrict__ AO)
{
  __shared__ u16 lK[3][64 * 64];     // [key][dh] swz ^(key&7)   24KB
  __shared__ u16 lV[3][64 * 64];     // [d][key]  swz ^(d&7)     24KB => 48KB

  const int phys = blockIdx.x;            // 512 blocks
  const int xcd = phys & 7, s = phys >> 3;
  const int bh = xcd * 8 + (s >> 3);
  const int pr = s & 7;
  const int qa = pr, qbt = 15 - pr;       // the two 128-row q-tiles of this block
  const int b = bh >> 4, h = bh & 15;

  const int tid = threadIdx.x, w = tid >> 6, lane = tid & 63;
  const int g = lane >> 4, q16 = lane & 15;

  const float* Bkb = Bk + (size_t)bh * L_;

  int kcol[2], vcol[4];
#pragma unroll
  for (int kk = 0; kk < 2; ++kk) kcol[kk] = ((kk * 4 + g) ^ (q16 & 7)) << 4;
#pragma unroll
  for (int t = 0; t < 4; ++t)
    vcol[t] = (((2 * t + (g >> 1)) ^ (q16 & 7)) << 4) + (g & 1) * 8;

  const int nkA = (qa + 1) * 2;
  const int nkB = (qbt + 1) * 2;

  auto STAGE = [&](int gst, int nb) {
    const int kt = (gst < nkA) ? gst : gst - nkA;
    const int kg0 = kt * 64;
    const int r8 = tid >> 3, cc = tid & 7;
    gload16(Kb + ((size_t)bh * L_ + kg0 + r8) * 64 + ((cc ^ (r8 & 7)) * 8),
            (char*)lK[nb] + tid * 16);
    gload16(Vt + ((size_t)(bh * 64 + r8)) * L_ + kg0 + ((cc ^ (r8 & 7)) * 8),
            (char*)lV[nb] + tid * 16);
  };

  auto BODY = [&](bf16x8 (&qf)[2], f32x4 (&o)[4], float& l_r, float mn,
                  int qrow, int kg0, int cur) {
    f32x4 sv[4];
#pragma unroll
    for (int t = 0; t < 4; ++t)
      sv[t] = *(const f32x4*)(Bkb + kg0 + t * 16 + g * 4);

    __builtin_amdgcn_s_setprio(1);
#pragma unroll
    for (int t = 0; t < 4; ++t) {
      const char* krow = (const char*)lK[cur] + t * 2048 + q16 * 128;
#pragma unroll
      for (int kk = 0; kk < 2; ++kk) {
        bf16x8 kf = *(const bf16x8*)(krow + kcol[kk]);
        sv[t] = __builtin_amdgcn_mfma_f32_16x16x32_bf16(kf, qf[kk], sv[t], 0, 0, 0);
      }
    }
    __builtin_amdgcn_s_setprio(0);

    if (kg0 + 63 > qrow) {
      const int qg = qrow + q16;
#pragma unroll
      for (int t = 0; t < 4; ++t)
#pragma unroll
        for (int r = 0; r < 4; ++r)
          sv[t][r] = (kg0 + t * 16 + g * 4 + r <= qg) ? sv[t][r] : -INFINITY;
    }

    float rs = 0.f;
#pragma unroll
    for (int t = 0; t < 4; ++t)
#pragma unroll
      for (int r = 0; r < 4; ++r) {
        float pv = exp2_fast(sv[t][r] - mn);
        sv[t][r] = pv;
        rs += pv;
      }
    l_r += rs;

    s16x4 pf[4];
#pragma unroll
    for (int t = 0; t < 4; ++t) {
      s16x4 pp;
      pp[0] = (short)f2bf(sv[t][0]); pp[1] = (short)f2bf(sv[t][1]);
      pp[2] = (short)f2bf(sv[t][2]); pp[3] = (short)f2bf(sv[t][3]);
      pf[t] = pp;
    }

    __builtin_amdgcn_s_setprio(1);
#pragma unroll
    for (int t = 0; t < 4; ++t) {
      const char* vrow = (const char*)lV[cur] + q16 * 128 + vcol[t];
#pragma unroll
      for (int db = 0; db < 4; ++db) {
        s16x4 vf = *(const s16x4*)(vrow + db * 2048);
        o[db] = mfma16(vf, pf[t], o[db]);
      }
    }
    __builtin_amdgcn_s_setprio(0);
  };

  auto EPI = [&](f32x4 (&o)[4], float l_r, int qt) {
    float lt = l_r + __shfl_xor(l_r, 16);
    lt += __shfl_xor(lt, 32);
    float inv = 1.f / lt;
    u16* dst = AO + ((size_t)(b * L_ + qt * 128 + w * 16 + q16)) * DM_ + h * 64 + g * 4;
#pragma unroll
    for (int db = 0; db < 4; ++db) {
      u32x2 pk;
      pk[0] = (u32)f2bf(o[db][0] * inv) | ((u32)f2bf(o[db][1] * inv) << 16);
      pk[1] = (u32)f2bf(o[db][2] * inv) | ((u32)f2bf(o[db][3] * inv) << 16);
      *(u32x2*)(dst + db * 16) = pk;
    }
  };

  STAGE(0, 0);
  STAGE(1, 1);
  asm volatile("s_waitcnt vmcnt(2) lgkmcnt(0)" ::: "memory");
  __builtin_amdgcn_s_barrier();
  __builtin_amdgcn_sched_barrier(0);

  // ================= tile A =================
  {
    const int qrow = qa * 128 + w * 16;
    const int mkt = (qrow + 79) >> 6;
    const float mn = Bkb[qrow + q16] + 8.f;
    bf16x8 qf[2];
    {
      const u16* Qr = Qb + ((size_t)bh * L_ + qrow + q16) * 64;
      qf[0] = *(const bf16x8*)(Qr + g * 8);
      qf[1] = *(const bf16x8*)(Qr + 32 + g * 8);
    }
    float l_r = 0.f;
    f32x4 o[4];
#pragma unroll
    for (int db = 0; db < 4; ++db) {
      o[db][0] = 0.f; o[db][1] = 0.f; o[db][2] = 0.f; o[db][3] = 0.f;
    }
    for (int st = 0; st < nkA; ++st) {
      const int cur = st % 3;
      STAGE(st + 2, (st + 2) % 3);
      if (st < mkt) BODY(qf, o, l_r, mn, qrow, st * 64, cur);
      asm volatile("s_waitcnt vmcnt(2) lgkmcnt(0)" ::: "memory");
      __builtin_amdgcn_s_barrier();
      __builtin_amdgcn_sched_barrier(0);
    }
    EPI(o, l_r, qa);
  }

  // ================= tile B =================
  {
    const int qrow = qbt * 128 + w * 16;
    const int mkt = (qrow + 79) >> 6;
    const float mn = Bkb[qrow + q16] + 8.f;
    bf16x8 qf[2];
    {
      const u16* Qr = Qb + ((size_t)bh * L_ + qrow + q16) * 64;
      qf[0] = *(const bf16x8*)(Qr + g * 8);
      qf[1] = *(const bf16x8*)(Qr + 32 + g * 8);
    }
    float l_r = 0.f;
    f32x4 o[4];
#pragma unroll
    for (int db = 0; db < 4; ++db) {
      o[db][0] = 0.f; o[db][1] = 0.f; o[db][2] = 0.f; o[db][3] = 0.f;
    }
    for (int kt = 0; kt < nkB; ++kt) {
      const int gst = nkA + kt;
      const int cur = gst % 3;
      const bool pf = (kt + 2 < nkB);
      if (pf) STAGE(gst + 2, (gst + 2) % 3);
      if (kt < mkt) BODY(qf, o, l_r, mn, qrow, kt * 64, cur);
      if (kt + 1 < nkB) {
        if (pf) asm volatile("s_waitcnt vmcnt(2) lgkmcnt(0)" ::: "memory");
        else    asm volatile("s_waitcnt vmcnt(0) lgkmcnt(0)" ::: "memory");
        __builtin_amdgcn_s_barrier();
        __builtin_amdgcn_sched_barrier(0);
      }
    }
    EPI(o, l_r, qbt);
  }
}

// ---------------- launcher ----------------
extern "C" void kernel_launch(void* const* d_in, const int* in_sizes, int n_in,
                              void* d_out, int out_size, void* d_ws, size_t ws_size,
                              hipStream_t stream) {
  const float* x    = (const float*)d_in[0];
  const float* ts   = (const float*)d_in[1];
  const float* mk   = (const float*)d_in[2];
  const float* Wqkv = (const float*)d_in[3];
  const float* bqkv = (const float*)d_in[4];
  const float* Wout = (const float*)d_in[5];
  const float* bout = (const float*)d_in[6];
  const float* dec  = (const float*)d_in[7];
  float* out = (float*)d_out;

  char* ws = (char*)d_ws;
  u16* xbf  = (u16*)(ws + 0);
  u16* wqbf = (u16*)(ws + 16777216);
  u16* wobf = (u16*)(ws + 23068672);
  u16* Qb   = (u16*)(ws + 25165824);
  u16* Kb   = (u16*)(ws + 41943040);
  u16* Vt   = (u16*)(ws + 58720256);
  u16* AO   = (u16*)(ws + 75497472);
  float* Bk = (float*)(ws + 92274688);   // 64*2048*4 = 512KB

  cvt3<<<dim3((NX4 + NQ4 + NO4) / 256), 256, 0, stream>>>(x, Wqkv, Wout, xbf, wqbf, wobf);

  bias_fill<<<dim3(64 * 2048 / 256), 256, 0, stream>>>(ts, mk, dec, Bk);

  // QKV GEMM: 256x256 tile, grid = (8192/256)*(3072/256) = 32*12 = 384 blocks
  gemm_qkv<<<dim3(384), 512, 0, stream>>>(xbf, wqbf, bqkv, Qb, Kb, Vt);

  attn_fwd<<<dim3(512), 512, 0, stream>>>(Qb, Kb, Vt, Bk, AO);

  // output GEMM: 256x128 tile, grid = (8192/256)*(1024/128) = 256 blocks
  gemm_bf16<<<dim3(256), 512, 0, stream>>>(
      AO, wobf, bout, 8192, 1024, 1024, 1, nullptr, nullptr, nullptr, out);
}

// Round 12
// 171.611 us; speedup vs baseline: 1.2864x; 1.0161x over previous
//
#include <hip/hip_runtime.h>
#include <stdint.h>
#include <math.h>

#define B_   4
#define L_   2048
#define H_   16
#define DH_  64
#define DM_  1024

typedef __bf16 bf16;
typedef __attribute__((ext_vector_type(8))) __bf16 bf16x8;
typedef __attribute__((ext_vector_type(4))) float f32x4;
typedef __attribute__((ext_vector_type(4))) int i32x4;
typedef __attribute__((ext_vector_type(4))) short s16x4;
typedef unsigned short u16;
typedef unsigned int u32;
typedef __attribute__((ext_vector_type(2))) unsigned int u32x2;
typedef __attribute__((ext_vector_type(4))) unsigned short u16x4;

typedef unsigned int u32g __attribute__((address_space(1)));
typedef unsigned int u32l __attribute__((address_space(3)));

__device__ __forceinline__ u16 f2bf(float f) {
  return __builtin_bit_cast(u16, (bf16)f);   // fptrunc = RNE
}

// 2^x via the HW transcendental unit (scores are kept in log2 units)
__device__ __forceinline__ float exp2_fast(float x) {
  float r; asm("v_exp_f32 %0, %1" : "=v"(r) : "v"(x)); return r;
}

// async global->LDS 16B; LDS dest must be wave-uniform base + lane*16
__device__ __forceinline__ void gload16(const void* g, void* l) {
  __builtin_amdgcn_global_load_lds((const u32g*)g, (u32l*)l, 16, 0, 0);
}

// K=16 bf16 MFMA: A/B are 4 bf16 per lane with k=(lane>>4)*4+j — this matches
// the C-layout of the QK 16x16x32 MFMA, so P needs NO cross-lane transpose.
__device__ __forceinline__ f32x4 mfma16(s16x4 a, s16x4 b, f32x4 c) {
#if __has_builtin(__builtin_amdgcn_mfma_f32_16x16x16bf16_1k)
  return __builtin_amdgcn_mfma_f32_16x16x16bf16_1k(a, b, c, 0, 0, 0);
#else
  asm volatile("v_mfma_f32_16x16x16_bf16 %0, %1, %2, %0\n\ts_nop 7\n\ts_nop 2"
               : "+v"(c) : "v"(a), "v"(b));
  return c;
#endif
}

// ---------------- fused f32 -> bf16 conversion + bias table (one launch) ----------------
#define NX4 2097152                  // 8192*1024/4
#define NQ4 786432                   // 3072*1024/4
#define NO4 262144                   // 1024*1024/4
#define NTOT4 (NX4 + NQ4 + NO4)      // 3145728
__global__ __launch_bounds__(256) void cvt3b(const float* __restrict__ x,
                                             const float* __restrict__ wq,
                                             const float* __restrict__ wo,
                                             u16* __restrict__ xb, u16* __restrict__ wqb,
                                             u16* __restrict__ wob,
                                             const float* __restrict__ ts,
                                             const float* __restrict__ msk,
                                             const float* __restrict__ decay,
                                             float* __restrict__ Bk) {
  int i = blockIdx.x * 256 + threadIdx.x;    // grid = NTOT4 + 64*2048 threads
  if (i >= NTOT4) {
    // bias tail: Bk[bh][l] (log2 units)
    int j = i - NTOT4;                       // 0 .. 131071
    int bh = j >> 11, l = j & (L_ - 1);
    int b = bh >> 4, h = bh & 15;
    float dc24 = log1pf(__expf(decay[h])) * (1.0f / 24.0f) * 1.44269504f;
    float tv = ts[b * L_ + l], mv = msk[b * L_ + l];
    Bk[j] = (mv != 0.f) ? dc24 * tv : -INFINITY;
    return;
  }
  const float* src; u16* dst; int j;
  if (i < NX4)            { src = x;  dst = xb;  j = i; }
  else if (i < NX4 + NQ4) { src = wq; dst = wqb; j = i - NX4; }
  else                    { src = wo; dst = wob; j = i - NX4 - NQ4; }
  f32x4 v = ((const f32x4*)src)[j];
  u16x4 o;
  o[0] = f2bf(v[0]); o[1] = f2bf(v[1]); o[2] = f2bf(v[2]); o[3] = f2bf(v[3]);
  ((u16x4*)dst)[j] = o;
}

// ---------------- QKV GEMM (R20 verbatim): 256x256, 8 waves of 128x64 ----------------
__global__ __launch_bounds__(512) void gemm_qkv(
    const u16* __restrict__ A, const u16* __restrict__ Bm, const float* __restrict__ bias,
    u16* __restrict__ Qb, u16* __restrict__ Kb, u16* __restrict__ Vt)
{
  __shared__ char smem[135168];     // 2 x (A 32KB + B 32KB) = 128KB; epi ltr[256][264]
  u16* ltr = (u16*)smem;
  const int K = 1024, nk = 16;

  const int tid = threadIdx.x;
  const int nwg = gridDim.x;              // 384, %8==0
  int idx = blockIdx.x;
  idx = (idx & 7) * (nwg >> 3) + (idx >> 3);
  const int nbx = 12;                     // N=3072 / 256
  const int bx = idx % nbx, by = idx / nbx;
  const int m0 = by << 8, n0 = bx << 8;

  const int lane = tid & 63, w = tid >> 6;
  const int g = lane >> 4, col = lane & 15;
  const int wr = w >> 2, wc = w & 3;      // 2M x 4N; per-wave C = 128 x 64

  f32x4 acc[8][4];
#pragma unroll
  for (int mt = 0; mt < 8; ++mt)
#pragma unroll
    for (int nt = 0; nt < 4; ++nt) {
      acc[mt][nt][0] = 0.f; acc[mt][nt][1] = 0.f;
      acc[mt][nt][2] = 0.f; acc[mt][nt][3] = 0.f;
    }

  auto SA = [&](int kt, int nb, int q) {
    char* dA = smem + (nb << 16);
    int c = (q << 9) + tid;
    int row = c >> 3, cc = c & 7;
    gload16(A + (size_t)(m0 + row) * K + (kt << 6) + ((cc ^ (row & 7)) << 3), dA + c * 16);
  };
  auto SB = [&](int kt, int nb, int q) {
    char* dB = smem + (nb << 16) + 32768;
    int c = (q << 9) + tid;
    int row = c >> 3, cc = c & 7;
    gload16(Bm + (size_t)(n0 + row) * K + (kt << 6) + ((cc ^ (row & 7)) << 3), dB + c * 16);
  };

  SA(0, 0, 0); SA(0, 0, 1); SA(0, 0, 2); SA(0, 0, 3);
  SB(0, 0, 0); SB(0, 0, 1); SB(0, 0, 2); SB(0, 0, 3);
  SA(1, 1, 0); SA(1, 1, 2); SB(1, 1, 0); SB(1, 1, 1); SA(1, 1, 1); SA(1, 1, 3);
  asm volatile("s_waitcnt vmcnt(6)" ::: "memory");   // tile 0 landed
  __builtin_amdgcn_s_barrier();

  for (int t = 0; t < nk; ++t) {
    const char* bufA = smem + ((t & 1) << 16);
    const char* bufB = bufA + 32768;
    const int nbN = (t + 1) & 1;

    auto RDA = [&](int mt, int kk) {
      int row = wr * 128 + mt * 16 + col;
      return *(const bf16x8*)(bufA + row * 128 + ((((kk << 2) + g) ^ (row & 7)) << 4));
    };
    auto RDB = [&](int nt, int kk) {
      int row = wc * 64 + nt * 16 + col;
      return *(const bf16x8*)(bufB + row * 128 + ((((kk << 2) + g) ^ (row & 7)) << 4));
    };

    bf16x8 af[4][2], bfr[4][2];

    // ---- P1: (m-lo, n-lo) ----
#pragma unroll
    for (int mi = 0; mi < 4; ++mi) { af[mi][0] = RDA(mi, 0); af[mi][1] = RDA(mi, 1); }
#pragma unroll
    for (int ni = 0; ni < 2; ++ni) { bfr[ni][0] = RDB(ni, 0); bfr[ni][1] = RDB(ni, 1); }
    if (t + 1 < nk) { SB(t + 1, nbN, 2); SB(t + 1, nbN, 3); }
    __builtin_amdgcn_s_barrier();
    asm volatile("s_waitcnt lgkmcnt(0)" ::: "memory");
    __builtin_amdgcn_sched_barrier(0);
    __builtin_amdgcn_s_setprio(1);
#pragma unroll
    for (int mi = 0; mi < 4; ++mi)
#pragma unroll
      for (int ni = 0; ni < 2; ++ni)
#pragma unroll
        for (int kk = 0; kk < 2; ++kk)
          acc[mi][ni] = __builtin_amdgcn_mfma_f32_16x16x32_bf16(af[mi][kk], bfr[ni][kk], acc[mi][ni], 0, 0, 0);
    __builtin_amdgcn_s_setprio(0);
    __builtin_amdgcn_s_barrier();

    // ---- P2: (m-lo, n-hi) ----
#pragma unroll
    for (int ni = 2; ni < 4; ++ni) { bfr[ni][0] = RDB(ni, 0); bfr[ni][1] = RDB(ni, 1); }
    if (t + 2 < nk) { SA(t + 2, t & 1, 0); SA(t + 2, t & 1, 2); }
    __builtin_amdgcn_s_barrier();
    asm volatile("s_waitcnt lgkmcnt(0)" ::: "memory");
    __builtin_amdgcn_sched_barrier(0);
    __builtin_amdgcn_s_setprio(1);
#pragma unroll
    for (int mi = 0; mi < 4; ++mi)
#pragma unroll
      for (int ni = 2; ni < 4; ++ni)
#pragma unroll
        for (int kk = 0; kk < 2; ++kk)
          acc[mi][ni] = __builtin_amdgcn_mfma_f32_16x16x32_bf16(af[mi][kk], bfr[ni][kk], acc[mi][ni], 0, 0, 0);
    __builtin_amdgcn_s_setprio(0);
    __builtin_amdgcn_s_barrier();

    // ---- P3: (m-hi, n-hi) ----
#pragma unroll
    for (int mi = 0; mi < 4; ++mi) { af[mi][0] = RDA(mi + 4, 0); af[mi][1] = RDA(mi + 4, 1); }
    if (t + 2 < nk) { SB(t + 2, t & 1, 0); SB(t + 2, t & 1, 1); }
    __builtin_amdgcn_s_barrier();
    asm volatile("s_waitcnt lgkmcnt(0)" ::: "memory");
    __builtin_amdgcn_sched_barrier(0);
    __builtin_amdgcn_s_setprio(1);
#pragma unroll
    for (int mi = 0; mi < 4; ++mi)
#pragma unroll
      for (int ni = 2; ni < 4; ++ni)
#pragma unroll
        for (int kk = 0; kk < 2; ++kk)
          acc[mi + 4][ni] = __builtin_amdgcn_mfma_f32_16x16x32_bf16(af[mi][kk], bfr[ni][kk], acc[mi + 4][ni], 0, 0, 0);
    __builtin_amdgcn_s_setprio(0);
    __builtin_amdgcn_s_barrier();

    // ---- P4: (m-hi, n-lo) ----
    if (t + 2 < nk) { SA(t + 2, t & 1, 1); SA(t + 2, t & 1, 3); }
    __builtin_amdgcn_s_setprio(1);
#pragma unroll
    for (int mi = 0; mi < 4; ++mi)
#pragma unroll
      for (int ni = 0; ni < 2; ++ni)
#pragma unroll
        for (int kk = 0; kk < 2; ++kk)
          acc[mi + 4][ni] = __builtin_amdgcn_mfma_f32_16x16x32_bf16(af[mi][kk], bfr[ni][kk], acc[mi + 4][ni], 0, 0, 0);
    __builtin_amdgcn_s_setprio(0);
    if (t + 2 < nk) asm volatile("s_waitcnt vmcnt(6)" ::: "memory");
    else            asm volatile("s_waitcnt vmcnt(0)" ::: "memory");
    __builtin_amdgcn_s_barrier();
  }

  // ---- mode-0 epilogue via padded LDS transpose: ltr[256][264] u16 ----
  const int type = n0 >> 10;
  const float qsc = (type == 0) ? 0.125f * 1.44269504f : 1.0f;
#pragma unroll
  for (int nt = 0; nt < 4; ++nt) {
    int nn = wc * 64 + nt * 16 + col;
    float bv = bias[n0 + nn];
#pragma unroll
    for (int mt = 0; mt < 8; ++mt) {
      int mm = wr * 128 + mt * 16 + g * 4;
#pragma unroll
      for (int r = 0; r < 4; ++r) {
        u16 hv = f2bf((acc[mt][nt][r] + bv) * qsc);
        if (type < 2) ltr[(mm + r) * 264 + nn] = hv;
        else          ltr[nn * 264 + (mm + r)] = hv;
      }
    }
  }
  __syncthreads();
  if (type < 2) {
#pragma unroll
    for (int it = 0; it < 16; ++it) {
      int cid = tid + it * 512;
      int rrow = cid >> 5, cc = cid & 31;
      i32x4 v = *(const i32x4*)((const char*)ltr + rrow * 528 + cc * 16);
      int token = m0 + rrow;
      int bb = token >> 11, ll = token & (L_ - 1);
      int gn = n0 + cc * 8;
      int head = (gn & 1023) >> 6, d = gn & 63;
      u16* dst = (type == 0) ? Qb : Kb;
      *(i32x4*)(dst + ((size_t)((bb * H_ + head) * L_ + ll)) * 64 + d) = v;
    }
  } else {
#pragma unroll
    for (int it = 0; it < 16; ++it) {
      int cid = tid + it * 512;
      int rrow = cid >> 5, cc = cid & 31;
      i32x4 v = *(const i32x4*)((const char*)ltr + rrow * 528 + cc * 16);
      int gn = n0 + rrow;
      int head = (gn & 1023) >> 6, d = gn & 63;
      int token0 = m0 + cc * 8;
      int bb = token0 >> 11, ll = token0 & (L_ - 1);
      *(i32x4*)(Vt + ((size_t)((bb * H_ + head) * DH_ + d)) * L_ + ll) = v;
    }
  }
}

// ---------------- bf16 GEMM (R17 verbatim — mode-1 output GEMM) ----------------
__global__ __launch_bounds__(512) void gemm_bf16(
    const u16* __restrict__ A, const u16* __restrict__ Bm, const float* __restrict__ bias,
    int M, int N, int K, int mode,
    u16* __restrict__ Qb, u16* __restrict__ Kb, u16* __restrict__ Vt, float* __restrict__ Cout)
{
  __shared__ char smem[147456];
  const int tid = threadIdx.x;
  const int nwg = gridDim.x;
  int idx = blockIdx.x;
  idx = (idx & 7) * (nwg >> 3) + (idx >> 3);
  const int nbx = N >> 7;
  const int bx = idx % nbx, by = idx / nbx;
  const int m0 = by << 8, n0 = bx << 7;

  const int lane = tid & 63, w = tid >> 6;
  const int g = lane >> 4, col = lane & 15;
  const int wr = w >> 1, wc = w & 1;

  f32x4 acc[4][4];
#pragma unroll
  for (int mt = 0; mt < 4; ++mt)
#pragma unroll
    for (int nt = 0; nt < 4; ++nt) {
      acc[mt][nt][0] = 0.f; acc[mt][nt][1] = 0.f;
      acc[mt][nt][2] = 0.f; acc[mt][nt][3] = 0.f;
    }

  auto STAGE_A = [&](int kt, int nb, int hh) {
    char* dA = smem + nb * 49152;
    const int k0 = kt << 6;
#pragma unroll
    for (int pp = hh * 2; pp < hh * 2 + 2; ++pp) {
      int c = tid + pp * 512;
      int row = c >> 3, cc = c & 7;
      gload16(A + (size_t)(m0 + row) * K + k0 + ((cc ^ (row & 7)) << 3), dA + c * 16);
    }
  };
  auto STAGE_B = [&](int kt, int nb) {
    char* dB = smem + nb * 49152 + 32768;
    const int k0 = kt << 6;
#pragma unroll
    for (int pp = 0; pp < 2; ++pp) {
      int c = tid + pp * 512;
      int row = c >> 3, cc = c & 7;
      gload16(Bm + (size_t)(n0 + row) * K + k0 + ((cc ^ (row & 7)) << 3), dB + c * 16);
    }
  };

  STAGE_A(0, 0, 0); STAGE_A(0, 0, 1); STAGE_B(0, 0);
  STAGE_A(1, 1, 0); STAGE_A(1, 1, 1); STAGE_B(1, 1);
  asm volatile("s_waitcnt vmcnt(6)" ::: "memory");
  __builtin_amdgcn_s_barrier();

  const int nk = K >> 6;
  for (int t = 0; t < nk; ++t) {
    const char* bufA = smem + (t % 3) * 49152;
    const char* bufB = bufA + 32768;
    const bool pf = (t + 2 < nk);
    const int nb2 = (t + 2) % 3;

    bf16x8 af[4][2], bfr[4][2];
    auto RDA = [&](int mt, int kk) {
      int row = wr * 64 + mt * 16 + col;
      return *(const bf16x8*)(bufA + row * 128 + ((((kk << 2) + g) ^ (row & 7)) << 4));
    };
    auto RDB = [&](int nt, int kk) {
      int row = wc * 64 + nt * 16 + col;
      return *(const bf16x8*)(bufB + row * 128 + ((((kk << 2) + g) ^ (row & 7)) << 4));
    };
    auto QUAD = [&](int qm, int qn) {
      __builtin_amdgcn_s_setprio(1);
#pragma unroll
      for (int mi = 0; mi < 2; ++mi)
#pragma unroll
        for (int ni = 0; ni < 2; ++ni)
#pragma unroll
          for (int kk = 0; kk < 2; ++kk)
            acc[qm * 2 + mi][qn * 2 + ni] = __builtin_amdgcn_mfma_f32_16x16x32_bf16(
                af[qm * 2 + mi][kk], bfr[qn * 2 + ni][kk], acc[qm * 2 + mi][qn * 2 + ni], 0, 0, 0);
      __builtin_amdgcn_s_setprio(0);
    };

#pragma unroll
    for (int mi = 0; mi < 2; ++mi) { af[mi][0] = RDA(mi, 0); af[mi][1] = RDA(mi, 1); }
#pragma unroll
    for (int ni = 0; ni < 2; ++ni) { bfr[ni][0] = RDB(ni, 0); bfr[ni][1] = RDB(ni, 1); }
    if (pf) STAGE_A(t + 2, nb2, 0);
    __builtin_amdgcn_s_barrier();
    asm volatile("s_waitcnt lgkmcnt(0)" ::: "memory");
    __builtin_amdgcn_sched_barrier(0);
    QUAD(0, 0);
    __builtin_amdgcn_s_barrier();

#pragma unroll
    for (int ni = 2; ni < 4; ++ni) { bfr[ni][0] = RDB(ni, 0); bfr[ni][1] = RDB(ni, 1); }
    if (pf) STAGE_A(t + 2, nb2, 1);
    __builtin_amdgcn_s_barrier();
    asm volatile("s_waitcnt lgkmcnt(0)" ::: "memory");
    __builtin_amdgcn_sched_barrier(0);
    QUAD(0, 1);
    __builtin_amdgcn_s_barrier();

#pragma unroll
    for (int mi = 2; mi < 4; ++mi) { af[mi][0] = RDA(mi, 0); af[mi][1] = RDA(mi, 1); }
    if (pf) STAGE_B(t + 2, nb2);
    __builtin_amdgcn_s_barrier();
    asm volatile("s_waitcnt lgkmcnt(0)" ::: "memory");
    __builtin_amdgcn_sched_barrier(0);
    QUAD(1, 1);
    __builtin_amdgcn_s_barrier();

    QUAD(1, 0);
    if (pf)              asm volatile("s_waitcnt vmcnt(6)" ::: "memory");
    else if (t + 1 < nk) asm volatile("s_waitcnt vmcnt(0)" ::: "memory");
    __builtin_amdgcn_s_barrier();
  }

#pragma unroll
  for (int nt = 0; nt < 4; ++nt) {
    int gn = n0 + wc * 64 + nt * 16 + col;
    float bv = bias[gn];
#pragma unroll
    for (int mt = 0; mt < 4; ++mt) {
      int mbase = m0 + wr * 64 + mt * 16 + g * 4;
#pragma unroll
      for (int r = 0; r < 4; ++r)
        Cout[(size_t)(mbase + r) * N + gn] = acc[mt][nt][r] + bv;
    }
  }
}

// ---------------- fused temporal flash attention ----------------
// R21 = R18 + T15 double-pipeline: step t runs QK(t)+softmax(t), then PV(t-1)
// — softmax VALU of step t and PV MFMA of step t-1 are dataflow-independent,
// so the scheduler overlaps vector and matrix pipes WITHIN a wave (the kernel
// is latency-bound: no pipe >46% busy at 4 waves/SIMD).
//  * depth-1 prefetch, 3 buffers: at step t, bufs hold {t-1 (V for deferred
//    PV), t, t+1 (staging)}; (t+1)-(t-1) = 2 mod 3 -> no alias.
//  * pf state: two named arrays + explicit copy (static indexing, rule #20);
//    pvb (V-buffer index) is runtime but only feeds address arithmetic.
//  * extra barrier at the A->B seam protects the tail-PV's V buffer from B's
//    first STAGE.
__global__ __launch_bounds__(512, 2) void attn_fwd(
    const u16* __restrict__ Qb, const u16* __restrict__ Kb, const u16* __restrict__ Vt,
    const float* __restrict__ Bk, u16* __restrict__ AO)
{
  __shared__ u16 lK[3][64 * 64];     // [key][dh] swz ^(key&7)   24KB
  __shared__ u16 lV[3][64 * 64];     // [d][key]  swz ^(d&7)     24KB => 48KB

  const int phys = blockIdx.x;            // 512 blocks
  const int xcd = phys & 7, s = phys >> 3;
  const int bh = xcd * 8 + (s >> 3);
  const int pr = s & 7;
  const int qa = pr, qbt = 15 - pr;
  const int b = bh >> 4, h = bh & 15;

  const int tid = threadIdx.x, w = tid >> 6, lane = tid & 63;
  const int g = lane >> 4, q16 = lane & 15;

  const float* Bkb = Bk + (size_t)bh * L_;

  int kcol[2], vcol[4];
#pragma unroll
  for (int kk = 0; kk < 2; ++kk) kcol[kk] = ((kk * 4 + g) ^ (q16 & 7)) << 4;
#pragma unroll
  for (int t = 0; t < 4; ++t)
    vcol[t] = (((2 * t + (g >> 1)) ^ (q16 & 7)) << 4) + (g & 1) * 8;

  const int nkA = (qa + 1) * 2;
  const int nkB = (qbt + 1) * 2;

  auto STAGE = [&](int gst, int nb) {
    const int kt = (gst < nkA) ? gst : gst - nkA;
    const int kg0 = kt * 64;
    const int r8 = tid >> 3, cc = tid & 7;
    gload16(Kb + ((size_t)bh * L_ + kg0 + r8) * 64 + ((cc ^ (r8 & 7)) * 8),
            (char*)lK[nb] + tid * 16);
    gload16(Vt + ((size_t)(bh * 64 + r8)) * L_ + kg0 + ((cc ^ (r8 & 7)) * 8),
            (char*)lV[nb] + tid * 16);
  };

  // QK + static-normalizer softmax + pack (no PV)
  auto QKBODY = [&](bf16x8 (&qf)[2], float& l_r, float mn,
                    int qrow, int kg0, int cur, s16x4 (&pf)[4]) {
    f32x4 sv[4];
#pragma unroll
    for (int t = 0; t < 4; ++t)
      sv[t] = *(const f32x4*)(Bkb + kg0 + t * 16 + g * 4);

    __builtin_amdgcn_s_setprio(1);
#pragma unroll
    for (int t = 0; t < 4; ++t) {
      const char* krow = (const char*)lK[cur] + t * 2048 + q16 * 128;
#pragma unroll
      for (int kk = 0; kk < 2; ++kk) {
        bf16x8 kf = *(const bf16x8*)(krow + kcol[kk]);
        sv[t] = __builtin_amdgcn_mfma_f32_16x16x32_bf16(kf, qf[kk], sv[t], 0, 0, 0);
      }
    }
    __builtin_amdgcn_s_setprio(0);

    if (kg0 + 63 > qrow) {
      const int qg = qrow + q16;
#pragma unroll
      for (int t = 0; t < 4; ++t)
#pragma unroll
        for (int r = 0; r < 4; ++r)
          sv[t][r] = (kg0 + t * 16 + g * 4 + r <= qg) ? sv[t][r] : -INFINITY;
    }

    float rs = 0.f;
#pragma unroll
    for (int t = 0; t < 4; ++t) {
      s16x4 pp;
#pragma unroll
      for (int r = 0; r < 4; ++r) {
        float pv = exp2_fast(sv[t][r] - mn);
        rs += pv;
        pp[r] = (short)f2bf(pv);
      }
      pf[t] = pp;
    }
    l_r += rs;
  };

  // deferred PV on the previous step's P, reading V from buffer vb
  auto PVBODY = [&](f32x4 (&o)[4], s16x4 (&pf)[4], int vb) {
    __builtin_amdgcn_s_setprio(1);
#pragma unroll
    for (int t = 0; t < 4; ++t) {
      const char* vrow = (const char*)lV[vb] + q16 * 128 + vcol[t];
#pragma unroll
      for (int db = 0; db < 4; ++db) {
        s16x4 vf = *(const s16x4*)(vrow + db * 2048);
        o[db] = mfma16(vf, pf[t], o[db]);
      }
    }
    __builtin_amdgcn_s_setprio(0);
  };

  auto EPI = [&](f32x4 (&o)[4], float l_r, int qt) {
    float lt = l_r + __shfl_xor(l_r, 16);
    lt += __shfl_xor(lt, 32);
    float inv = 1.f / lt;
    u16* dst = AO + ((size_t)(b * L_ + qt * 128 + w * 16 + q16)) * DM_ + h * 64 + g * 4;
#pragma unroll
    for (int db = 0; db < 4; ++db) {
      u32x2 pk;
      pk[0] = (u32)f2bf(o[db][0] * inv) | ((u32)f2bf(o[db][1] * inv) << 16);
      pk[1] = (u32)f2bf(o[db][2] * inv) | ((u32)f2bf(o[db][3] * inv) << 16);
      *(u32x2*)(dst + db * 16) = pk;
    }
  };

  // ---- prologue: depth-1 fill ----
  STAGE(0, 0);
  asm volatile("s_waitcnt vmcnt(0) lgkmcnt(0)" ::: "memory");
  __builtin_amdgcn_s_barrier();
  __builtin_amdgcn_sched_barrier(0);

  // ================= tile A =================
  {
    const int qrow = qa * 128 + w * 16;
    const int mkt = (qrow + 79) >> 6;
    const float mn = Bkb[qrow + q16] + 8.f;
    bf16x8 qf[2];
    {
      const u16* Qr = Qb + ((size_t)bh * L_ + qrow + q16) * 64;
      qf[0] = *(const bf16x8*)(Qr + g * 8);
      qf[1] = *(const bf16x8*)(Qr + 32 + g * 8);
    }
    float l_r = 0.f;
    f32x4 o[4];
#pragma unroll
    for (int db = 0; db < 4; ++db) {
      o[db][0] = 0.f; o[db][1] = 0.f; o[db][2] = 0.f; o[db][3] = 0.f;
    }
    s16x4 pfP[4];
    int pvb = 0;
    bool pvalid = false;
    for (int st = 0; st < nkA; ++st) {
      const int cur = st % 3;
      STAGE(st + 1, (st + 1) % 3);        // st+1 <= nkA maps across the seam
      const bool doqk = st < mkt;
      s16x4 pfC[4];
      if (doqk) QKBODY(qf, l_r, mn, qrow, st * 64, cur, pfC);
      if (pvalid) PVBODY(o, pfP, pvb);
      if (doqk) {
#pragma unroll
        for (int t = 0; t < 4; ++t) pfP[t] = pfC[t];
        pvb = cur;
      }
      pvalid = doqk;
      asm volatile("s_waitcnt vmcnt(0) lgkmcnt(0)" ::: "memory");
      __builtin_amdgcn_s_barrier();
      __builtin_amdgcn_sched_barrier(0);
    }
    if (pvalid) PVBODY(o, pfP, pvb);      // tail PV (tile mkt-1; buffer intact)
    EPI(o, l_r, qa);
  }
  __builtin_amdgcn_s_barrier();           // protect tail-PV reads from B's STAGE

  // ================= tile B =================
  {
    const int qrow = qbt * 128 + w * 16;
    const int mkt = (qrow + 79) >> 6;
    const float mn = Bkb[qrow + q16] + 8.f;
    bf16x8 qf[2];
    {
      const u16* Qr = Qb + ((size_t)bh * L_ + qrow + q16) * 64;
      qf[0] = *(const bf16x8*)(Qr + g * 8);
      qf[1] = *(const bf16x8*)(Qr + 32 + g * 8);
    }
    float l_r = 0.f;
    f32x4 o[4];
#pragma unroll
    for (int db = 0; db < 4; ++db) {
      o[db][0] = 0.f; o[db][1] = 0.f; o[db][2] = 0.f; o[db][3] = 0.f;
    }
    s16x4 pfP[4];
    int pvb = 0;
    bool pvalid = false;
    for (int kt = 0; kt < nkB; ++kt) {
      const int gst = nkA + kt;
      const int cur = gst % 3;
      if (kt + 1 < nkB) STAGE(gst + 1, (gst + 1) % 3);
      const bool doqk = kt < mkt;
      s16x4 pfC[4];
      if (doqk) QKBODY(qf, l_r, mn, qrow, kt * 64, cur, pfC);
      if (pvalid) PVBODY(o, pfP, pvb);
      if (doqk) {
#pragma unroll
        for (int t = 0; t < 4; ++t) pfP[t] = pfC[t];
        pvb = cur;
      }
      pvalid = doqk;
      if (kt + 1 < nkB) {
        asm volatile("s_waitcnt vmcnt(0) lgkmcnt(0)" ::: "memory");
        __builtin_amdgcn_s_barrier();
        __builtin_amdgcn_sched_barrier(0);
      }
    }
    if (pvalid) PVBODY(o, pfP, pvb);
    EPI(o, l_r, qbt);
  }
}

// ---------------- launcher ----------------
extern "C" void kernel_launch(void* const* d_in, const int* in_sizes, int n_in,
                              void* d_out, int out_size, void* d_ws, size_t ws_size,
                              hipStream_t stream) {
  const float* x    = (const float*)d_in[0];
  const float* ts   = (const float*)d_in[1];
  const float* mk   = (const float*)d_in[2];
  const float* Wqkv = (const float*)d_in[3];
  const float* bqkv = (const float*)d_in[4];
  const float* Wout = (const float*)d_in[5];
  const float* bout = (const float*)d_in[6];
  const float* dec  = (const float*)d_in[7];
  float* out = (float*)d_out;

  char* ws = (char*)d_ws;
  u16* xbf  = (u16*)(ws + 0);
  u16* wqbf = (u16*)(ws + 16777216);
  u16* wobf = (u16*)(ws + 23068672);
  u16* Qb   = (u16*)(ws + 25165824);
  u16* Kb   = (u16*)(ws + 41943040);
  u16* Vt   = (u16*)(ws + 58720256);
  u16* AO   = (u16*)(ws + 75497472);
  float* Bk = (float*)(ws + 92274688);   // 64*2048*4 = 512KB

  // cvt + bias fused: 12288 cvt blocks + 512 bias blocks
  cvt3b<<<dim3((NTOT4 + 64 * 2048) / 256), 256, 0, stream>>>(
      x, Wqkv, Wout, xbf, wqbf, wobf, ts, mk, dec, Bk);

  // QKV GEMM: 256x256 tile, grid = (8192/256)*(3072/256) = 384 blocks
  gemm_qkv<<<dim3(384), 512, 0, stream>>>(xbf, wqbf, bqkv, Qb, Kb, Vt);

  attn_fwd<<<dim3(512), 512, 0, stream>>>(Qb, Kb, Vt, Bk, AO);

  // output GEMM: 256x128 tile, grid = (8192/256)*(1024/128) = 256 blocks
  gemm_bf16<<<dim3(256), 512, 0, stream>>>(
      AO, wobf, bout, 8192, 1024, 1024, 1, nullptr, nullptr, nullptr, out);
}